// Round 1
// baseline (683.489 us; speedup 1.0000x reference)
//
#include <hip/hip_runtime.h>
#include <hip/hip_bf16.h>
#include <cstdint>

// Problem constants (match reference setup_inputs()).
constexpr int N_NODES = 50000;
constexpr int N_EDGES = 800000;
constexpr int F_IN    = 128;
constexpr int F_HID   = 256;
constexpr int F_OUT   = 256;
constexpr int N_COLS  = 256;   // output cols of both GEMMs (HID == OUT == 256)

// ---------------------------------------------------------------------------
// CSR build
// ---------------------------------------------------------------------------
__global__ void deg_kernel(const int* __restrict__ dst, int* __restrict__ deg) {
    int e = blockIdx.x * blockDim.x + threadIdx.x;
    if (e < N_EDGES) atomicAdd(&deg[dst[e]], 1);
}

// Single-block exclusive scan over deg[] -> row_ptr[], plus inv_deg.
__global__ __launch_bounds__(1024) void scan_kernel(const int* __restrict__ deg,
                                                    int* __restrict__ row_ptr,
                                                    float* __restrict__ inv_deg) {
    __shared__ int part[1024];
    const int tid = threadIdx.x;
    const int CH  = (N_NODES + 1023) / 1024;   // 49
    const int start = tid * CH;

    int s = 0;
    for (int i = 0; i < CH; ++i) {
        int idx = start + i;
        if (idx < N_NODES) s += deg[idx];
    }
    part[tid] = s;
    __syncthreads();
    // Hillis-Steele inclusive scan in LDS
    for (int off = 1; off < 1024; off <<= 1) {
        int t = 0;
        if (tid >= off) t = part[tid - off];
        __syncthreads();
        part[tid] += t;
        __syncthreads();
    }
    int run = part[tid] - s;   // exclusive base for this chunk
    for (int i = 0; i < CH; ++i) {
        int idx = start + i;
        if (idx < N_NODES) {
            int d = deg[idx];
            row_ptr[idx] = run;
            inv_deg[idx] = (d > 0) ? (1.0f / (float)d) : 0.0f;
            run += d;
        }
    }
    if (tid == 1023) row_ptr[N_NODES] = part[1023];
}

__global__ void fill_kernel(const int* __restrict__ src, const int* __restrict__ dst,
                            const int* __restrict__ row_ptr, int* __restrict__ cursor,
                            int* __restrict__ col) {
    int e = blockIdx.x * blockDim.x + threadIdx.x;
    if (e < N_EDGES) {
        int d = dst[e];
        int pos = atomicAdd(&cursor[d], 1);
        col[row_ptr[d] + pos] = src[e];
    }
}

// ---------------------------------------------------------------------------
// Mean aggregation over CSR: out[n] = inv_deg[n] * sum_{e in row n} feat[col[e]]
// One block per node, one thread per feature.
// ---------------------------------------------------------------------------
template <int F>
__global__ __launch_bounds__(F) void agg_mean(const float* __restrict__ feat,
                                              const int* __restrict__ rp,
                                              const int* __restrict__ col,
                                              const float* __restrict__ invd,
                                              float* __restrict__ out) {
    const int n = blockIdx.x;
    const int f = threadIdx.x;
    const int beg = rp[n], end = rp[n + 1];
    float acc = 0.f;
    int e = beg;
    for (; e + 1 < end; e += 2) {
        int nb0 = col[e];
        int nb1 = col[e + 1];
        acc += feat[(size_t)nb0 * F + f];
        acc += feat[(size_t)nb1 * F + f];
    }
    if (e < end) acc += feat[(size_t)col[e] * F + f];
    out[(size_t)n * F + f] = acc * invd[n];
}

// ---------------------------------------------------------------------------
// C = relu( A1 @ W[0:K1] + A2 @ W[K1:K1+K2] + bias ),  C: [M, 256] row-major.
// fp32 register-tiled GEMM: BM=128, BN=64, BK=16, 256 threads, 8x4 per thread.
// ---------------------------------------------------------------------------
template <int K1, int K2>
__global__ __launch_bounds__(256) void gemm_concat_relu(const float* __restrict__ A1,
                                                        const float* __restrict__ A2,
                                                        const float* __restrict__ W,
                                                        const float* __restrict__ bias,
                                                        float* __restrict__ C, int M) {
    constexpr int BM = 128, BN = 64, BK = 16;
    __shared__ float As[BK][BM + 4];
    __shared__ float Ws[BK][BN + 4];

    const int tid = threadIdx.x;
    const int tx = tid & 15;        // 0..15 -> 4 output cols each
    const int ty = tid >> 4;        // 0..15 -> 8 output rows each
    const int m0 = blockIdx.x * BM;
    const int n0 = blockIdx.y * BN;

    float acc[8][4] = {};

    constexpr int K = K1 + K2;
    for (int k0 = 0; k0 < K; k0 += BK) {
        const float* Ap;
        int kA, KldA;
        if (k0 < K1) { Ap = A1; kA = k0;       KldA = K1; }
        else         { Ap = A2; kA = k0 - K1;  KldA = K2; }

        // A tile: BM x BK (2048 floats), 2 float4 per thread, stored k-major.
        {
            const int c = (tid & 3) * 4;   // k offset within tile
            const int r = tid >> 2;        // 0..63
            #pragma unroll
            for (int rr = 0; rr < 2; ++rr) {
                const int row = r + rr * 64;
                const int gm = m0 + row;
                float4 v = make_float4(0.f, 0.f, 0.f, 0.f);
                if (gm < M) v = *reinterpret_cast<const float4*>(&Ap[(size_t)gm * KldA + kA + c]);
                As[c + 0][row] = v.x;
                As[c + 1][row] = v.y;
                As[c + 2][row] = v.z;
                As[c + 3][row] = v.w;
            }
        }
        // W tile: BK x BN (1024 floats), 1 float4 per thread.
        {
            const int r2 = tid >> 4;          // 0..15
            const int cw = (tid & 15) * 4;    // 0..60
            float4 v = *reinterpret_cast<const float4*>(&W[(size_t)(k0 + r2) * N_COLS + n0 + cw]);
            *reinterpret_cast<float4*>(&Ws[r2][cw]) = v;
        }
        __syncthreads();

        #pragma unroll
        for (int kk = 0; kk < BK; ++kk) {
            float4 a0 = *reinterpret_cast<const float4*>(&As[kk][ty * 8]);
            float4 a1 = *reinterpret_cast<const float4*>(&As[kk][ty * 8 + 4]);
            float4 w  = *reinterpret_cast<const float4*>(&Ws[kk][tx * 4]);
            float a[8] = {a0.x, a0.y, a0.z, a0.w, a1.x, a1.y, a1.z, a1.w};
            float wv[4] = {w.x, w.y, w.z, w.w};
            #pragma unroll
            for (int i = 0; i < 8; ++i)
                #pragma unroll
                for (int j = 0; j < 4; ++j)
                    acc[i][j] = fmaf(a[i], wv[j], acc[i][j]);
        }
        __syncthreads();
    }

    // Epilogue: bias + relu, float4 stores.
    float4 bv = *reinterpret_cast<const float4*>(&bias[n0 + tx * 4]);
    const float bb[4] = {bv.x, bv.y, bv.z, bv.w};
    #pragma unroll
    for (int i = 0; i < 8; ++i) {
        const int gm = m0 + ty * 8 + i;
        if (gm < M) {
            float4 o;
            o.x = fmaxf(acc[i][0] + bb[0], 0.f);
            o.y = fmaxf(acc[i][1] + bb[1], 0.f);
            o.z = fmaxf(acc[i][2] + bb[2], 0.f);
            o.w = fmaxf(acc[i][3] + bb[3], 0.f);
            *reinterpret_cast<float4*>(&C[(size_t)gm * N_COLS + n0 + tx * 4]) = o;
        }
    }
}

// ---------------------------------------------------------------------------
// Host launch
// ---------------------------------------------------------------------------
extern "C" void kernel_launch(void* const* d_in, const int* in_sizes, int n_in,
                              void* d_out, int out_size, void* d_ws, size_t ws_size,
                              hipStream_t stream) {
    const float* x   = (const float*)d_in[0];
    const int*   src = (const int*)d_in[1];
    const int*   dst = (const int*)d_in[2];
    const float* W1  = (const float*)d_in[3];
    const float* b1  = (const float*)d_in[4];
    const float* W2  = (const float*)d_in[5];
    const float* b2  = (const float*)d_in[6];
    float* out = (float*)d_out;

    // Workspace carve-up (all 256B-aligned).
    char* ws = (char*)d_ws;
    size_t off = 0;
    auto carve = [&](size_t bytes) {
        char* p = ws + off;
        off = (off + bytes + 255) & ~(size_t)255;
        return p;
    };
    int*   deg     = (int*)carve(sizeof(int) * N_NODES);
    int*   row_ptr = (int*)carve(sizeof(int) * (N_NODES + 1));
    int*   cursor  = (int*)carve(sizeof(int) * N_NODES);
    float* inv_deg = (float*)carve(sizeof(float) * N_NODES);
    int*   col     = (int*)carve(sizeof(int) * N_EDGES);
    float* h1      = (float*)carve(sizeof(float) * (size_t)N_NODES * F_HID);   // 51.2 MB
    float* buf2    = (float*)carve(sizeof(float) * (size_t)N_NODES * F_HID);   // 51.2 MB (xn then h1n)
    float* xn  = buf2;   // [N, 128] — dead after gemm1
    float* h1n = buf2;   // [N, 256] — written by agg2 (after gemm1 completes)

    // --- CSR build ---
    hipMemsetAsync(deg, 0, sizeof(int) * N_NODES, stream);
    hipMemsetAsync(cursor, 0, sizeof(int) * N_NODES, stream);
    {
        dim3 g((N_EDGES + 255) / 256);
        deg_kernel<<<g, 256, 0, stream>>>(dst, deg);
    }
    scan_kernel<<<1, 1024, 0, stream>>>(deg, row_ptr, inv_deg);
    {
        dim3 g((N_EDGES + 255) / 256);
        fill_kernel<<<g, 256, 0, stream>>>(src, dst, row_ptr, cursor, col);
    }

    // --- Layer 1 ---
    agg_mean<F_IN><<<N_NODES, F_IN, 0, stream>>>(x, row_ptr, col, inv_deg, xn);
    {
        dim3 g((N_NODES + 127) / 128, N_COLS / 64);
        gemm_concat_relu<F_IN, F_IN><<<g, 256, 0, stream>>>(x, xn, W1, b1, h1, N_NODES);
    }

    // --- Layer 2 ---
    agg_mean<F_HID><<<N_NODES, F_HID, 0, stream>>>(h1, row_ptr, col, inv_deg, h1n);
    {
        dim3 g((N_NODES + 127) / 128, N_COLS / 64);
        gemm_concat_relu<F_HID, F_HID><<<g, 256, 0, stream>>>(h1, h1n, W2, b2, out, N_NODES);
    }
}

// Round 2
// 361.380 us; speedup vs baseline: 1.8913x; 1.8913x over previous
//
#include <hip/hip_runtime.h>
#include <hip/hip_bf16.h>
#include <cstdint>

constexpr int N_NODES = 50000;
constexpr int N_EDGES = 800000;
constexpr int F_IN    = 128;
constexpr int F_HID   = 256;
constexpr int N_COLS  = 256;
constexpr int M_PAD   = 50048;   // 391 * 128

typedef unsigned short u16;
typedef u16   ushort4v __attribute__((ext_vector_type(4)));
typedef u16   ushort8v __attribute__((ext_vector_type(8)));
typedef __bf16 bf16x8  __attribute__((ext_vector_type(8)));
typedef float  f32x4   __attribute__((ext_vector_type(4)));

__device__ __forceinline__ float bf2f(u16 u) {
    return __uint_as_float(((uint32_t)u) << 16);
}
__device__ __forceinline__ u16 f2bf(float f) {
    uint32_t u = __float_as_uint(f);
    uint32_t r = u + 0x7FFFu + ((u >> 16) & 1u);   // RNE
    return (u16)(r >> 16);
}

// async global->LDS, 16B per lane. LDS dest must be wave-uniform base; HW adds lane*16.
__device__ __forceinline__ void gll16(const void* g, void* l) {
    __builtin_amdgcn_global_load_lds(
        (const __attribute__((address_space(1))) uint32_t*)(uintptr_t)g,
        (__attribute__((address_space(3))) uint32_t*)(uintptr_t)l,
        16, 0, 0);
}

// ---------------------------------------------------------------------------
// CSR build
// ---------------------------------------------------------------------------
__global__ void deg_kernel(const int* __restrict__ dst, int* __restrict__ deg) {
    int e = blockIdx.x * blockDim.x + threadIdx.x;
    if (e < N_EDGES) atomicAdd(&deg[dst[e]], 1);
}

__global__ __launch_bounds__(1024) void scan_kernel(const int* __restrict__ deg,
                                                    int* __restrict__ row_ptr,
                                                    float* __restrict__ inv_deg) {
    __shared__ int part[1024];
    const int tid = threadIdx.x;
    const int CH  = (N_NODES + 1023) / 1024;
    const int start = tid * CH;
    int s = 0;
    for (int i = 0; i < CH; ++i) {
        int idx = start + i;
        if (idx < N_NODES) s += deg[idx];
    }
    part[tid] = s;
    __syncthreads();
    for (int off = 1; off < 1024; off <<= 1) {
        int t = 0;
        if (tid >= off) t = part[tid - off];
        __syncthreads();
        part[tid] += t;
        __syncthreads();
    }
    int run = part[tid] - s;
    for (int i = 0; i < CH; ++i) {
        int idx = start + i;
        if (idx < N_NODES) {
            int d = deg[idx];
            row_ptr[idx] = run;
            inv_deg[idx] = (d > 0) ? (1.0f / (float)d) : 0.0f;
            run += d;
        }
    }
    if (tid == 1023) row_ptr[N_NODES] = part[1023];
}

__global__ void fill_kernel(const int* __restrict__ src, const int* __restrict__ dst,
                            const int* __restrict__ row_ptr, int* __restrict__ cursor,
                            int* __restrict__ col) {
    int e = blockIdx.x * blockDim.x + threadIdx.x;
    if (e < N_EDGES) {
        int d = dst[e];
        int pos = atomicAdd(&cursor[d], 1);
        col[row_ptr[d] + pos] = src[e];
    }
}

// ---------------------------------------------------------------------------
// fp32 -> bf16 convert (vectorized: 4 floats / thread)
// ---------------------------------------------------------------------------
__global__ __launch_bounds__(256) void f2bf_kernel(const float* __restrict__ in,
                                                   u16* __restrict__ out, int n4) {
    int i = blockIdx.x * blockDim.x + threadIdx.x;
    if (i < n4) {
        float4 v = *reinterpret_cast<const float4*>(&in[(size_t)i * 4]);
        ushort4v o;
        o.x = f2bf(v.x); o.y = f2bf(v.y); o.z = f2bf(v.z); o.w = f2bf(v.w);
        *reinterpret_cast<ushort4v*>(&out[(size_t)i * 4]) = o;
    }
}

// W [K][256] fp32 -> Wt [256][K] bf16
template <int K>
__global__ __launch_bounds__(256) void wtrans(const float* __restrict__ W,
                                              u16* __restrict__ Wt) {
    const int n = blockIdx.x;  // 0..255
    for (int k = threadIdx.x; k < K; k += 256)
        Wt[(size_t)n * K + k] = f2bf(W[(size_t)k * N_COLS + n]);
}

// ---------------------------------------------------------------------------
// Mean aggregation, bf16 in / bf16 out, fp32 accumulation.
// F/8 lanes per node, 16B gathers.
// ---------------------------------------------------------------------------
template <int F>
__global__ __launch_bounds__(256) void agg_mean_bf16(const u16* __restrict__ feat,
                                                     const int* __restrict__ rp,
                                                     const int* __restrict__ col,
                                                     const float* __restrict__ invd,
                                                     u16* __restrict__ out) {
    constexpr int LPN = F / 8;        // lanes per node
    constexpr int NPB = 256 / LPN;    // nodes per block
    const int slot = threadIdx.x / LPN;
    const int ln   = threadIdx.x % LPN;
    const int n = blockIdx.x * NPB + slot;
    if (n >= N_NODES) return;
    const int beg = rp[n], end = rp[n + 1];
    float acc[8] = {};
    int e = beg;
    for (; e + 1 < end; e += 2) {
        int nb0 = col[e];
        int nb1 = col[e + 1];
        ushort8v v0 = *reinterpret_cast<const ushort8v*>(&feat[(size_t)nb0 * F + ln * 8]);
        ushort8v v1 = *reinterpret_cast<const ushort8v*>(&feat[(size_t)nb1 * F + ln * 8]);
        #pragma unroll
        for (int j = 0; j < 8; ++j) acc[j] += bf2f(v0[j]);
        #pragma unroll
        for (int j = 0; j < 8; ++j) acc[j] += bf2f(v1[j]);
    }
    if (e < end) {
        ushort8v v = *reinterpret_cast<const ushort8v*>(&feat[(size_t)col[e] * F + ln * 8]);
        #pragma unroll
        for (int j = 0; j < 8; ++j) acc[j] += bf2f(v[j]);
    }
    const float s = invd[n];
    ushort8v o;
    #pragma unroll
    for (int j = 0; j < 8; ++j) o[j] = f2bf(acc[j] * s);
    *reinterpret_cast<ushort8v*>(&out[(size_t)n * F + ln * 8]) = o;
}

// ---------------------------------------------------------------------------
// C = relu([A1 | A2] @ W + b), bf16 MFMA, m97 structure.
// A1,A2: [M_PAD][K1] bf16 row-major. Bt: [256][2*K1] bf16 row-major (W^T).
// 128x128 tile, BK=32, 256 threads = 4 waves, each wave 64x64 via 4x4 frags.
// ---------------------------------------------------------------------------
template <int K1, bool OUT_BF16>
__global__ __launch_bounds__(256) void gemm_bt_bf16(const u16* __restrict__ A1,
                                                    const u16* __restrict__ A2,
                                                    const u16* __restrict__ Bt,
                                                    const float* __restrict__ bias,
                                                    void* __restrict__ Cout, int M) {
    constexpr int K = 2 * K1;
    __shared__ u16 As[128 * 32];
    __shared__ u16 Bs[128 * 32];

    const int t  = threadIdx.x;
    const int wv = t >> 6;          // wave 0..3
    const int l  = t & 63;
    const int m0 = blockIdx.x * 128;
    const int n0 = blockIdx.y * 128;

    // staging coords: thread t loads 16B at LDS-linear t*16 (rows 0..63), +4096B (rows 64..127)
    const int sr = t >> 2;          // 0..63
    const int sk = (t & 3) * 8;     // k element offset
    // fragment coords
    const int lr = l & 15;
    const int lk = (l >> 4) * 8;
    const int wr = (wv >> 1) * 64;
    const int wc = (wv & 1) * 64;

    f32x4 acc[4][4] = {};

    #pragma unroll 1
    for (int kt = 0; kt < K / 32; ++kt) {
        const int kg = kt * 32;
        const u16* Ab;
        int ka;
        if (kg < K1) { Ab = A1; ka = kg; }
        else         { Ab = A2; ka = kg - K1; }

        gll16(&Ab[(size_t)(m0 + sr) * K1 + ka + sk],       &As[wv * 512]);
        gll16(&Ab[(size_t)(m0 + sr + 64) * K1 + ka + sk],  &As[2048 + wv * 512]);
        gll16(&Bt[(size_t)(n0 + sr) * K + kg + sk],        &Bs[wv * 512]);
        gll16(&Bt[(size_t)(n0 + sr + 64) * K + kg + sk],   &Bs[2048 + wv * 512]);
        __syncthreads();

        bf16x8 af[4], bfr[4];
        #pragma unroll
        for (int m = 0; m < 4; ++m)
            af[m] = *reinterpret_cast<const bf16x8*>(&As[(wr + m * 16 + lr) * 32 + lk]);
        #pragma unroll
        for (int n = 0; n < 4; ++n)
            bfr[n] = *reinterpret_cast<const bf16x8*>(&Bs[(wc + n * 16 + lr) * 32 + lk]);

        #pragma unroll
        for (int m = 0; m < 4; ++m)
            #pragma unroll
            for (int n = 0; n < 4; ++n)
                acc[m][n] = __builtin_amdgcn_mfma_f32_16x16x32_bf16(af[m], bfr[n], acc[m][n], 0, 0, 0);
        __syncthreads();
    }

    // epilogue: C/D layout col = l&15, row = (l>>4)*4 + r
    const int orow = (l >> 4) * 4;
    float bcol[4];
    #pragma unroll
    for (int n = 0; n < 4; ++n) bcol[n] = bias[n0 + wc + n * 16 + lr];

    #pragma unroll
    for (int m = 0; m < 4; ++m) {
        #pragma unroll
        for (int r = 0; r < 4; ++r) {
            const int row = m0 + wr + m * 16 + orow + r;
            if (row < M) {
                #pragma unroll
                for (int n = 0; n < 4; ++n) {
                    const int cg = n0 + wc + n * 16 + lr;
                    float v = fmaxf(acc[m][n][r] + bcol[n], 0.f);
                    if (OUT_BF16)
                        ((u16*)Cout)[(size_t)row * N_COLS + cg] = f2bf(v);
                    else
                        ((float*)Cout)[(size_t)row * N_COLS + cg] = v;
                }
            }
        }
    }
}

// ---------------------------------------------------------------------------
// Host launch
// ---------------------------------------------------------------------------
extern "C" void kernel_launch(void* const* d_in, const int* in_sizes, int n_in,
                              void* d_out, int out_size, void* d_ws, size_t ws_size,
                              hipStream_t stream) {
    const float* x   = (const float*)d_in[0];
    const int*   src = (const int*)d_in[1];
    const int*   dst = (const int*)d_in[2];
    const float* W1  = (const float*)d_in[3];
    const float* b1  = (const float*)d_in[4];
    const float* W2  = (const float*)d_in[5];
    const float* b2  = (const float*)d_in[6];
    float* out = (float*)d_out;

    char* ws = (char*)d_ws;
    size_t off = 0;
    auto carve = [&](size_t bytes) {
        char* p = ws + off;
        off = (off + bytes + 255) & ~(size_t)255;
        return p;
    };
    int*   deg     = (int*)carve(sizeof(int) * N_NODES);
    int*   row_ptr = (int*)carve(sizeof(int) * (N_NODES + 1));
    int*   cursor  = (int*)carve(sizeof(int) * N_NODES);
    float* inv_deg = (float*)carve(sizeof(float) * N_NODES);
    int*   col     = (int*)carve(sizeof(int) * N_EDGES);
    u16*   xb      = (u16*)carve(sizeof(u16) * (size_t)M_PAD * F_IN);
    u16*   xnb     = (u16*)carve(sizeof(u16) * (size_t)M_PAD * F_IN);
    u16*   h1b     = (u16*)carve(sizeof(u16) * (size_t)M_PAD * F_HID);
    u16*   h1nb    = (u16*)carve(sizeof(u16) * (size_t)M_PAD * F_HID);
    u16*   W1t     = (u16*)carve(sizeof(u16) * 256 * 256);
    u16*   W2t     = (u16*)carve(sizeof(u16) * 256 * 512);

    // --- CSR build ---
    hipMemsetAsync(deg, 0, sizeof(int) * N_NODES, stream);
    hipMemsetAsync(cursor, 0, sizeof(int) * N_NODES, stream);
    deg_kernel<<<dim3((N_EDGES + 255) / 256), 256, 0, stream>>>(dst, deg);
    scan_kernel<<<1, 1024, 0, stream>>>(deg, row_ptr, inv_deg);
    fill_kernel<<<dim3((N_EDGES + 255) / 256), 256, 0, stream>>>(src, dst, row_ptr, cursor, col);

    // --- bf16 conversions ---
    f2bf_kernel<<<dim3((N_NODES * F_IN / 4 + 255) / 256), 256, 0, stream>>>(x, xb, N_NODES * F_IN / 4);
    wtrans<256><<<dim3(256), 256, 0, stream>>>(W1, W1t);
    wtrans<512><<<dim3(256), 256, 0, stream>>>(W2, W2t);

    // --- Layer 1 ---
    agg_mean_bf16<F_IN><<<dim3((N_NODES + 15) / 16), 256, 0, stream>>>(xb, row_ptr, col, inv_deg, xnb);
    gemm_bt_bf16<128, true><<<dim3(M_PAD / 128, 2), 256, 0, stream>>>(xb, xnb, W1t, b1, h1b, N_NODES);

    // --- Layer 2 ---
    agg_mean_bf16<F_HID><<<dim3((N_NODES + 7) / 8), 256, 0, stream>>>(h1b, row_ptr, col, inv_deg, h1nb);
    gemm_bt_bf16<256, false><<<dim3(M_PAD / 128, 2), 256, 0, stream>>>(h1b, h1nb, W2t, b2, out, N_NODES);
}

// Round 3
// 250.908 us; speedup vs baseline: 2.7241x; 1.4403x over previous
//
#include <hip/hip_runtime.h>
#include <hip/hip_bf16.h>
#include <cstdint>

constexpr int N_NODES = 50000;
constexpr int N_EDGES = 800000;
constexpr int F_IN    = 128;
constexpr int F_HID   = 256;
constexpr int N_COLS  = 256;
constexpr int M_PAD   = 50048;   // 391 * 128
constexpr int NB_SCAN = (N_NODES + 255) / 256;   // 196 blocks

typedef unsigned short u16;
typedef u16   ushort4v __attribute__((ext_vector_type(4)));
typedef u16   ushort8v __attribute__((ext_vector_type(8)));
typedef __bf16 bf16x8  __attribute__((ext_vector_type(8)));
typedef float  f32x4   __attribute__((ext_vector_type(4)));

__device__ __forceinline__ float bf2f(u16 u) {
    return __uint_as_float(((uint32_t)u) << 16);
}
__device__ __forceinline__ u16 f2bf(float f) {
    uint32_t u = __float_as_uint(f);
    uint32_t r = u + 0x7FFFu + ((u >> 16) & 1u);   // RNE
    return (u16)(r >> 16);
}

// async global->LDS, 16B per lane. LDS dest must be wave-uniform base; HW adds lane*16.
__device__ __forceinline__ void gll16(const void* g, void* l) {
    __builtin_amdgcn_global_load_lds(
        (const __attribute__((address_space(1))) uint32_t*)(uintptr_t)g,
        (__attribute__((address_space(3))) uint32_t*)(uintptr_t)l,
        16, 0, 0);
}

// ---------------------------------------------------------------------------
// CSR build
// ---------------------------------------------------------------------------
__global__ void deg_kernel(const int* __restrict__ dst, int* __restrict__ deg) {
    int e = blockIdx.x * blockDim.x + threadIdx.x;
    if (e < N_EDGES) atomicAdd(&deg[dst[e]], 1);
}

// Two-level scan, kernel 1: per-block (256 nodes) degree sum.
__global__ __launch_bounds__(256) void block_sum_kernel(const int* __restrict__ deg,
                                                        int* __restrict__ part) {
    const int n = blockIdx.x * 256 + threadIdx.x;
    int v = (n < N_NODES) ? deg[n] : 0;
    #pragma unroll
    for (int o = 32; o > 0; o >>= 1) v += __shfl_down(v, o, 64);
    __shared__ int s[4];
    if ((threadIdx.x & 63) == 0) s[threadIdx.x >> 6] = v;
    __syncthreads();
    if (threadIdx.x == 0) part[blockIdx.x] = s[0] + s[1] + s[2] + s[3];
}

// kernel 2: exclusive scan of the 196 partials (single small block).
__global__ __launch_bounds__(256) void part_scan_kernel(int* __restrict__ part,
                                                        int* __restrict__ row_ptr) {
    __shared__ int s[256];
    const int tid = threadIdx.x;
    int v = (tid < NB_SCAN) ? part[tid] : 0;
    s[tid] = v;
    __syncthreads();
    #pragma unroll
    for (int o = 1; o < 256; o <<= 1) {
        int t = 0;
        if (tid >= o) t = s[tid - o];
        __syncthreads();
        s[tid] += t;
        __syncthreads();
    }
    if (tid < NB_SCAN) part[tid] = s[tid] - v;   // exclusive base per block
    if (tid == 255) row_ptr[N_NODES] = s[255];   // total edge count
}

// kernel 3: per-block local exclusive scan + block base -> row_ptr, inv_deg.
__global__ __launch_bounds__(256) void row_ptr_kernel(const int* __restrict__ deg,
                                                      const int* __restrict__ part,
                                                      int* __restrict__ row_ptr,
                                                      float* __restrict__ inv_deg) {
    __shared__ int s[256];
    const int tid = threadIdx.x;
    const int n = blockIdx.x * 256 + tid;
    const int d = (n < N_NODES) ? deg[n] : 0;
    s[tid] = d;
    __syncthreads();
    #pragma unroll
    for (int o = 1; o < 256; o <<= 1) {
        int t = 0;
        if (tid >= o) t = s[tid - o];
        __syncthreads();
        s[tid] += t;
        __syncthreads();
    }
    if (n < N_NODES) {
        row_ptr[n] = part[blockIdx.x] + s[tid] - d;
        inv_deg[n] = (d > 0) ? (1.0f / (float)d) : 0.0f;
    }
}

__global__ void fill_kernel(const int* __restrict__ src, const int* __restrict__ dst,
                            const int* __restrict__ row_ptr, int* __restrict__ cursor,
                            int* __restrict__ col) {
    int e = blockIdx.x * blockDim.x + threadIdx.x;
    if (e < N_EDGES) {
        int d = dst[e];
        int pos = atomicAdd(&cursor[d], 1);
        col[row_ptr[d] + pos] = src[e];
    }
}

// ---------------------------------------------------------------------------
// fp32 -> bf16 convert (vectorized: 4 floats / thread)
// ---------------------------------------------------------------------------
__global__ __launch_bounds__(256) void f2bf_kernel(const float* __restrict__ in,
                                                   u16* __restrict__ out, int n4) {
    int i = blockIdx.x * blockDim.x + threadIdx.x;
    if (i < n4) {
        float4 v = *reinterpret_cast<const float4*>(&in[(size_t)i * 4]);
        ushort4v o;
        o.x = f2bf(v.x); o.y = f2bf(v.y); o.z = f2bf(v.z); o.w = f2bf(v.w);
        *reinterpret_cast<ushort4v*>(&out[(size_t)i * 4]) = o;
    }
}

// W [K][256] fp32 -> Wt [256][K] bf16
template <int K>
__global__ __launch_bounds__(256) void wtrans(const float* __restrict__ W,
                                              u16* __restrict__ Wt) {
    const int n = blockIdx.x;  // 0..255
    for (int k = threadIdx.x; k < K; k += 256)
        Wt[(size_t)n * K + k] = f2bf(W[(size_t)k * N_COLS + n]);
}

// ---------------------------------------------------------------------------
// Mean aggregation, bf16 in / bf16 out, fp32 accumulation.
// F/8 lanes per node, 16B gathers.
// ---------------------------------------------------------------------------
template <int F>
__global__ __launch_bounds__(256) void agg_mean_bf16(const u16* __restrict__ feat,
                                                     const int* __restrict__ rp,
                                                     const int* __restrict__ col,
                                                     const float* __restrict__ invd,
                                                     u16* __restrict__ out) {
    constexpr int LPN = F / 8;        // lanes per node
    constexpr int NPB = 256 / LPN;    // nodes per block
    const int slot = threadIdx.x / LPN;
    const int ln   = threadIdx.x % LPN;
    const int n = blockIdx.x * NPB + slot;
    if (n >= N_NODES) return;
    const int beg = rp[n], end = rp[n + 1];
    float acc[8] = {};
    int e = beg;
    for (; e + 1 < end; e += 2) {
        int nb0 = col[e];
        int nb1 = col[e + 1];
        ushort8v v0 = *reinterpret_cast<const ushort8v*>(&feat[(size_t)nb0 * F + ln * 8]);
        ushort8v v1 = *reinterpret_cast<const ushort8v*>(&feat[(size_t)nb1 * F + ln * 8]);
        #pragma unroll
        for (int j = 0; j < 8; ++j) acc[j] += bf2f(v0[j]);
        #pragma unroll
        for (int j = 0; j < 8; ++j) acc[j] += bf2f(v1[j]);
    }
    if (e < end) {
        ushort8v v = *reinterpret_cast<const ushort8v*>(&feat[(size_t)col[e] * F + ln * 8]);
        #pragma unroll
        for (int j = 0; j < 8; ++j) acc[j] += bf2f(v[j]);
    }
    const float s = invd[n];
    ushort8v o;
    #pragma unroll
    for (int j = 0; j < 8; ++j) o[j] = f2bf(acc[j] * s);
    *reinterpret_cast<ushort8v*>(&out[(size_t)n * F + ln * 8]) = o;
}

// ---------------------------------------------------------------------------
// C = relu([A1 | A2] @ W + b), bf16 MFMA, m97 structure.
// A1,A2: [M_PAD][K1] bf16 row-major. Bt: [256][2*K1] bf16 row-major (W^T).
// 128x128 tile, BK=32, 256 threads = 4 waves, each wave 64x64 via 4x4 frags.
// ---------------------------------------------------------------------------
template <int K1, bool OUT_BF16>
__global__ __launch_bounds__(256) void gemm_bt_bf16(const u16* __restrict__ A1,
                                                    const u16* __restrict__ A2,
                                                    const u16* __restrict__ Bt,
                                                    const float* __restrict__ bias,
                                                    void* __restrict__ Cout, int M) {
    constexpr int K = 2 * K1;
    __shared__ u16 As[128 * 32];
    __shared__ u16 Bs[128 * 32];

    const int t  = threadIdx.x;
    const int wv = t >> 6;          // wave 0..3
    const int l  = t & 63;
    const int m0 = blockIdx.x * 128;
    const int n0 = blockIdx.y * 128;

    const int sr = t >> 2;          // 0..63
    const int sk = (t & 3) * 8;     // k element offset
    const int lr = l & 15;
    const int lk = (l >> 4) * 8;
    const int wr = (wv >> 1) * 64;
    const int wc = (wv & 1) * 64;

    f32x4 acc[4][4] = {};

    #pragma unroll 1
    for (int kt = 0; kt < K / 32; ++kt) {
        const int kg = kt * 32;
        const u16* Ab;
        int ka;
        if (kg < K1) { Ab = A1; ka = kg; }
        else         { Ab = A2; ka = kg - K1; }

        gll16(&Ab[(size_t)(m0 + sr) * K1 + ka + sk],       &As[wv * 512]);
        gll16(&Ab[(size_t)(m0 + sr + 64) * K1 + ka + sk],  &As[2048 + wv * 512]);
        gll16(&Bt[(size_t)(n0 + sr) * K + kg + sk],        &Bs[wv * 512]);
        gll16(&Bt[(size_t)(n0 + sr + 64) * K + kg + sk],   &Bs[2048 + wv * 512]);
        __syncthreads();

        bf16x8 af[4], bfr[4];
        #pragma unroll
        for (int m = 0; m < 4; ++m)
            af[m] = *reinterpret_cast<const bf16x8*>(&As[(wr + m * 16 + lr) * 32 + lk]);
        #pragma unroll
        for (int n = 0; n < 4; ++n)
            bfr[n] = *reinterpret_cast<const bf16x8*>(&Bs[(wc + n * 16 + lr) * 32 + lk]);

        #pragma unroll
        for (int m = 0; m < 4; ++m)
            #pragma unroll
            for (int n = 0; n < 4; ++n)
                acc[m][n] = __builtin_amdgcn_mfma_f32_16x16x32_bf16(af[m], bfr[n], acc[m][n], 0, 0, 0);
        __syncthreads();
    }

    const int orow = (l >> 4) * 4;
    float bcol[4];
    #pragma unroll
    for (int n = 0; n < 4; ++n) bcol[n] = bias[n0 + wc + n * 16 + lr];

    #pragma unroll
    for (int m = 0; m < 4; ++m) {
        #pragma unroll
        for (int r = 0; r < 4; ++r) {
            const int row = m0 + wr + m * 16 + orow + r;
            if (row < M) {
                #pragma unroll
                for (int n = 0; n < 4; ++n) {
                    const int cg = n0 + wc + n * 16 + lr;
                    float v = fmaxf(acc[m][n][r] + bcol[n], 0.f);
                    if (OUT_BF16)
                        ((u16*)Cout)[(size_t)row * N_COLS + cg] = f2bf(v);
                    else
                        ((float*)Cout)[(size_t)row * N_COLS + cg] = v;
                }
            }
        }
    }
}

// ---------------------------------------------------------------------------
// Host launch
// ---------------------------------------------------------------------------
extern "C" void kernel_launch(void* const* d_in, const int* in_sizes, int n_in,
                              void* d_out, int out_size, void* d_ws, size_t ws_size,
                              hipStream_t stream) {
    const float* x   = (const float*)d_in[0];
    const int*   src = (const int*)d_in[1];
    const int*   dst = (const int*)d_in[2];
    const float* W1  = (const float*)d_in[3];
    const float* b1  = (const float*)d_in[4];
    const float* W2  = (const float*)d_in[5];
    const float* b2  = (const float*)d_in[6];
    float* out = (float*)d_out;

    char* ws = (char*)d_ws;
    size_t off = 0;
    auto carve = [&](size_t bytes) {
        char* p = ws + off;
        off = (off + bytes + 255) & ~(size_t)255;
        return p;
    };
    int*   deg     = (int*)carve(sizeof(int) * N_NODES);
    int*   row_ptr = (int*)carve(sizeof(int) * (N_NODES + 1));
    int*   cursor  = (int*)carve(sizeof(int) * N_NODES);
    int*   part    = (int*)carve(sizeof(int) * 256);
    float* inv_deg = (float*)carve(sizeof(float) * N_NODES);
    int*   col     = (int*)carve(sizeof(int) * N_EDGES);
    u16*   xb      = (u16*)carve(sizeof(u16) * (size_t)M_PAD * F_IN);
    u16*   xnb     = (u16*)carve(sizeof(u16) * (size_t)M_PAD * F_IN);
    u16*   h1b     = (u16*)carve(sizeof(u16) * (size_t)M_PAD * F_HID);
    u16*   h1nb    = (u16*)carve(sizeof(u16) * (size_t)M_PAD * F_HID);
    u16*   W1t     = (u16*)carve(sizeof(u16) * 256 * 256);
    u16*   W2t     = (u16*)carve(sizeof(u16) * 256 * 512);

    // --- CSR build ---
    hipMemsetAsync(deg, 0, sizeof(int) * N_NODES, stream);
    hipMemsetAsync(cursor, 0, sizeof(int) * N_NODES, stream);
    deg_kernel<<<dim3((N_EDGES + 255) / 256), 256, 0, stream>>>(dst, deg);
    block_sum_kernel<<<dim3(NB_SCAN), 256, 0, stream>>>(deg, part);
    part_scan_kernel<<<dim3(1), 256, 0, stream>>>(part, row_ptr);
    row_ptr_kernel<<<dim3(NB_SCAN), 256, 0, stream>>>(deg, part, row_ptr, inv_deg);
    fill_kernel<<<dim3((N_EDGES + 255) / 256), 256, 0, stream>>>(src, dst, row_ptr, cursor, col);

    // --- bf16 conversions ---
    f2bf_kernel<<<dim3((N_NODES * F_IN / 4 + 255) / 256), 256, 0, stream>>>(x, xb, N_NODES * F_IN / 4);
    wtrans<256><<<dim3(256), 256, 0, stream>>>(W1, W1t);
    wtrans<512><<<dim3(256), 256, 0, stream>>>(W2, W2t);

    // --- Layer 1 ---
    agg_mean_bf16<F_IN><<<dim3((N_NODES + 15) / 16), 256, 0, stream>>>(xb, row_ptr, col, inv_deg, xnb);
    gemm_bt_bf16<128, true><<<dim3(M_PAD / 128, 2), 256, 0, stream>>>(xb, xnb, W1t, b1, h1b, N_NODES);

    // --- Layer 2 ---
    agg_mean_bf16<F_HID><<<dim3((N_NODES + 7) / 8), 256, 0, stream>>>(h1b, row_ptr, col, inv_deg, h1nb);
    gemm_bt_bf16<256, false><<<dim3(M_PAD / 128, 2), 256, 0, stream>>>(h1b, h1nb, W2t, b2, out, N_NODES);
}

// Round 4
// 248.251 us; speedup vs baseline: 2.7532x; 1.0107x over previous
//
#include <hip/hip_runtime.h>
#include <hip/hip_bf16.h>
#include <cstdint>

constexpr int N_NODES = 50000;
constexpr int N_EDGES = 800000;
constexpr int F_IN    = 128;
constexpr int F_HID   = 256;
constexpr int N_COLS  = 256;
constexpr int M_PAD   = 50048;   // 391 * 128
constexpr int NB_SCAN = (N_NODES + 255) / 256;   // 196 blocks

typedef unsigned short u16;
typedef u16   ushort4v __attribute__((ext_vector_type(4)));
typedef u16   ushort8v __attribute__((ext_vector_type(8)));
typedef __bf16 bf16x8  __attribute__((ext_vector_type(8)));
typedef float  f32x4   __attribute__((ext_vector_type(4)));

__device__ __forceinline__ float bf2f(u16 u) {
    return __uint_as_float(((uint32_t)u) << 16);
}
__device__ __forceinline__ u16 f2bf(float f) {
    uint32_t u = __float_as_uint(f);
    uint32_t r = u + 0x7FFFu + ((u >> 16) & 1u);   // RNE
    return (u16)(r >> 16);
}

// async global->LDS, 16B per lane. LDS dest must be wave-uniform base; HW adds lane*16.
__device__ __forceinline__ void gll16(const void* g, void* l) {
    __builtin_amdgcn_global_load_lds(
        (const __attribute__((address_space(1))) uint32_t*)(uintptr_t)g,
        (__attribute__((address_space(3))) uint32_t*)(uintptr_t)l,
        16, 0, 0);
}

// ---------------------------------------------------------------------------
// CSR build
// ---------------------------------------------------------------------------
__global__ void deg_kernel(const int* __restrict__ dst, int* __restrict__ deg) {
    int e = blockIdx.x * blockDim.x + threadIdx.x;
    if (e < N_EDGES) atomicAdd(&deg[dst[e]], 1);
}

__global__ __launch_bounds__(256) void block_sum_kernel(const int* __restrict__ deg,
                                                        int* __restrict__ part) {
    const int n = blockIdx.x * 256 + threadIdx.x;
    int v = (n < N_NODES) ? deg[n] : 0;
    #pragma unroll
    for (int o = 32; o > 0; o >>= 1) v += __shfl_down(v, o, 64);
    __shared__ int s[4];
    if ((threadIdx.x & 63) == 0) s[threadIdx.x >> 6] = v;
    __syncthreads();
    if (threadIdx.x == 0) part[blockIdx.x] = s[0] + s[1] + s[2] + s[3];
}

__global__ __launch_bounds__(256) void part_scan_kernel(int* __restrict__ part,
                                                        int* __restrict__ row_ptr) {
    __shared__ int s[256];
    const int tid = threadIdx.x;
    int v = (tid < NB_SCAN) ? part[tid] : 0;
    s[tid] = v;
    __syncthreads();
    #pragma unroll
    for (int o = 1; o < 256; o <<= 1) {
        int t = 0;
        if (tid >= o) t = s[tid - o];
        __syncthreads();
        s[tid] += t;
        __syncthreads();
    }
    if (tid < NB_SCAN) part[tid] = s[tid] - v;
    if (tid == 255) row_ptr[N_NODES] = s[255];
}

__global__ __launch_bounds__(256) void row_ptr_kernel(const int* __restrict__ deg,
                                                      const int* __restrict__ part,
                                                      int* __restrict__ row_ptr,
                                                      float* __restrict__ inv_deg) {
    __shared__ int s[256];
    const int tid = threadIdx.x;
    const int n = blockIdx.x * 256 + tid;
    const int d = (n < N_NODES) ? deg[n] : 0;
    s[tid] = d;
    __syncthreads();
    #pragma unroll
    for (int o = 1; o < 256; o <<= 1) {
        int t = 0;
        if (tid >= o) t = s[tid - o];
        __syncthreads();
        s[tid] += t;
        __syncthreads();
    }
    if (n < N_NODES) {
        row_ptr[n] = part[blockIdx.x] + s[tid] - d;
        inv_deg[n] = (d > 0) ? (1.0f / (float)d) : 0.0f;
    }
}

__global__ void fill_kernel(const int* __restrict__ src, const int* __restrict__ dst,
                            const int* __restrict__ row_ptr, int* __restrict__ cursor,
                            int* __restrict__ col) {
    int e = blockIdx.x * blockDim.x + threadIdx.x;
    if (e < N_EDGES) {
        int d = dst[e];
        int pos = atomicAdd(&cursor[d], 1);
        col[row_ptr[d] + pos] = src[e];
    }
}

// ---------------------------------------------------------------------------
// fp32 -> bf16 convert (vectorized: 4 floats / thread)
// ---------------------------------------------------------------------------
__global__ __launch_bounds__(256) void f2bf_kernel(const float* __restrict__ in,
                                                   u16* __restrict__ out, int n4) {
    int i = blockIdx.x * blockDim.x + threadIdx.x;
    if (i < n4) {
        float4 v = *reinterpret_cast<const float4*>(&in[(size_t)i * 4]);
        ushort4v o;
        o.x = f2bf(v.x); o.y = f2bf(v.y); o.z = f2bf(v.z); o.w = f2bf(v.w);
        *reinterpret_cast<ushort4v*>(&out[(size_t)i * 4]) = o;
    }
}

// W [K][256] fp32 -> Wt [256][K] bf16
template <int K>
__global__ __launch_bounds__(256) void wtrans(const float* __restrict__ W,
                                              u16* __restrict__ Wt) {
    const int n = blockIdx.x;
    for (int k = threadIdx.x; k < K; k += 256)
        Wt[(size_t)n * K + k] = f2bf(W[(size_t)k * N_COLS + n]);
}

// ---------------------------------------------------------------------------
// Mean aggregation, bf16 in / bf16 out, fp32 accumulation.
// F/8 lanes per node, 16B gathers, 4 rows in flight (latency hiding).
// ---------------------------------------------------------------------------
template <int F>
__global__ __launch_bounds__(256) void agg_mean_bf16(const u16* __restrict__ feat,
                                                     const int* __restrict__ rp,
                                                     const int* __restrict__ col,
                                                     const float* __restrict__ invd,
                                                     u16* __restrict__ out) {
    constexpr int LPN = F / 8;        // lanes per node
    constexpr int NPB = 256 / LPN;    // nodes per block
    const int slot = threadIdx.x / LPN;
    const int ln   = threadIdx.x % LPN;
    const int n = blockIdx.x * NPB + slot;
    if (n >= N_NODES) return;
    const int beg = rp[n], end = rp[n + 1];
    float acc0[8] = {}, acc1[8] = {};
    int e = beg;
    // main loop: 4 independent row-gathers in flight per iteration
    for (; e + 3 < end; e += 4) {
        int nb0 = col[e];
        int nb1 = col[e + 1];
        int nb2 = col[e + 2];
        int nb3 = col[e + 3];
        ushort8v v0 = *reinterpret_cast<const ushort8v*>(&feat[(size_t)nb0 * F + ln * 8]);
        ushort8v v1 = *reinterpret_cast<const ushort8v*>(&feat[(size_t)nb1 * F + ln * 8]);
        ushort8v v2 = *reinterpret_cast<const ushort8v*>(&feat[(size_t)nb2 * F + ln * 8]);
        ushort8v v3 = *reinterpret_cast<const ushort8v*>(&feat[(size_t)nb3 * F + ln * 8]);
        #pragma unroll
        for (int j = 0; j < 8; ++j) acc0[j] += bf2f(v0[j]);
        #pragma unroll
        for (int j = 0; j < 8; ++j) acc1[j] += bf2f(v1[j]);
        #pragma unroll
        for (int j = 0; j < 8; ++j) acc0[j] += bf2f(v2[j]);
        #pragma unroll
        for (int j = 0; j < 8; ++j) acc1[j] += bf2f(v3[j]);
    }
    if (e + 1 < end) {
        int nb0 = col[e];
        int nb1 = col[e + 1];
        ushort8v v0 = *reinterpret_cast<const ushort8v*>(&feat[(size_t)nb0 * F + ln * 8]);
        ushort8v v1 = *reinterpret_cast<const ushort8v*>(&feat[(size_t)nb1 * F + ln * 8]);
        #pragma unroll
        for (int j = 0; j < 8; ++j) acc0[j] += bf2f(v0[j]);
        #pragma unroll
        for (int j = 0; j < 8; ++j) acc1[j] += bf2f(v1[j]);
        e += 2;
    }
    if (e < end) {
        ushort8v v = *reinterpret_cast<const ushort8v*>(&feat[(size_t)col[e] * F + ln * 8]);
        #pragma unroll
        for (int j = 0; j < 8; ++j) acc0[j] += bf2f(v[j]);
    }
    const float s = invd[n];
    ushort8v o;
    #pragma unroll
    for (int j = 0; j < 8; ++j) o[j] = f2bf((acc0[j] + acc1[j]) * s);
    *reinterpret_cast<ushort8v*>(&out[(size_t)n * F + ln * 8]) = o;
}

// ---------------------------------------------------------------------------
// C = relu([A1 | A2] @ W + b), bf16 MFMA, m97 structure.
// ---------------------------------------------------------------------------
template <int K1, bool OUT_BF16>
__global__ __launch_bounds__(256) void gemm_bt_bf16(const u16* __restrict__ A1,
                                                    const u16* __restrict__ A2,
                                                    const u16* __restrict__ Bt,
                                                    const float* __restrict__ bias,
                                                    void* __restrict__ Cout, int M) {
    constexpr int K = 2 * K1;
    __shared__ u16 As[128 * 32];
    __shared__ u16 Bs[128 * 32];

    const int t  = threadIdx.x;
    const int wv = t >> 6;
    const int l  = t & 63;
    const int m0 = blockIdx.x * 128;
    const int n0 = blockIdx.y * 128;

    const int sr = t >> 2;
    const int sk = (t & 3) * 8;
    const int lr = l & 15;
    const int lk = (l >> 4) * 8;
    const int wr = (wv >> 1) * 64;
    const int wc = (wv & 1) * 64;

    f32x4 acc[4][4] = {};

    #pragma unroll 1
    for (int kt = 0; kt < K / 32; ++kt) {
        const int kg = kt * 32;
        const u16* Ab;
        int ka;
        if (kg < K1) { Ab = A1; ka = kg; }
        else         { Ab = A2; ka = kg - K1; }

        gll16(&Ab[(size_t)(m0 + sr) * K1 + ka + sk],       &As[wv * 512]);
        gll16(&Ab[(size_t)(m0 + sr + 64) * K1 + ka + sk],  &As[2048 + wv * 512]);
        gll16(&Bt[(size_t)(n0 + sr) * K + kg + sk],        &Bs[wv * 512]);
        gll16(&Bt[(size_t)(n0 + sr + 64) * K + kg + sk],   &Bs[2048 + wv * 512]);
        __syncthreads();

        bf16x8 af[4], bfr[4];
        #pragma unroll
        for (int m = 0; m < 4; ++m)
            af[m] = *reinterpret_cast<const bf16x8*>(&As[(wr + m * 16 + lr) * 32 + lk]);
        #pragma unroll
        for (int n = 0; n < 4; ++n)
            bfr[n] = *reinterpret_cast<const bf16x8*>(&Bs[(wc + n * 16 + lr) * 32 + lk]);

        #pragma unroll
        for (int m = 0; m < 4; ++m)
            #pragma unroll
            for (int n = 0; n < 4; ++n)
                acc[m][n] = __builtin_amdgcn_mfma_f32_16x16x32_bf16(af[m], bfr[n], acc[m][n], 0, 0, 0);
        __syncthreads();
    }

    const int orow = (l >> 4) * 4;
    float bcol[4];
    #pragma unroll
    for (int n = 0; n < 4; ++n) bcol[n] = bias[n0 + wc + n * 16 + lr];

    #pragma unroll
    for (int m = 0; m < 4; ++m) {
        #pragma unroll
        for (int r = 0; r < 4; ++r) {
            const int row = m0 + wr + m * 16 + orow + r;
            if (row < M) {
                #pragma unroll
                for (int n = 0; n < 4; ++n) {
                    const int cg = n0 + wc + n * 16 + lr;
                    float v = fmaxf(acc[m][n][r] + bcol[n], 0.f);
                    if (OUT_BF16)
                        ((u16*)Cout)[(size_t)row * N_COLS + cg] = f2bf(v);
                    else
                        ((float*)Cout)[(size_t)row * N_COLS + cg] = v;
                }
            }
        }
    }
}

// ---------------------------------------------------------------------------
// Host launch
// ---------------------------------------------------------------------------
extern "C" void kernel_launch(void* const* d_in, const int* in_sizes, int n_in,
                              void* d_out, int out_size, void* d_ws, size_t ws_size,
                              hipStream_t stream) {
    const float* x   = (const float*)d_in[0];
    const int*   src = (const int*)d_in[1];
    const int*   dst = (const int*)d_in[2];
    const float* W1  = (const float*)d_in[3];
    const float* b1  = (const float*)d_in[4];
    const float* W2  = (const float*)d_in[5];
    const float* b2  = (const float*)d_in[6];
    float* out = (float*)d_out;

    char* ws = (char*)d_ws;
    size_t off = 0;
    auto carve = [&](size_t bytes) {
        char* p = ws + off;
        off = (off + bytes + 255) & ~(size_t)255;
        return p;
    };
    int*   deg     = (int*)carve(sizeof(int) * N_NODES);
    int*   row_ptr = (int*)carve(sizeof(int) * (N_NODES + 1));
    int*   cursor  = (int*)carve(sizeof(int) * N_NODES);
    int*   part    = (int*)carve(sizeof(int) * 256);
    float* inv_deg = (float*)carve(sizeof(float) * N_NODES);
    int*   col     = (int*)carve(sizeof(int) * N_EDGES);
    u16*   xb      = (u16*)carve(sizeof(u16) * (size_t)M_PAD * F_IN);
    u16*   xnb     = (u16*)carve(sizeof(u16) * (size_t)M_PAD * F_IN);
    u16*   h1b     = (u16*)carve(sizeof(u16) * (size_t)M_PAD * F_HID);
    u16*   h1nb    = (u16*)carve(sizeof(u16) * (size_t)M_PAD * F_HID);
    u16*   W1t     = (u16*)carve(sizeof(u16) * 256 * 256);
    u16*   W2t     = (u16*)carve(sizeof(u16) * 256 * 512);

    // --- CSR build ---
    hipMemsetAsync(deg, 0, sizeof(int) * N_NODES, stream);
    hipMemsetAsync(cursor, 0, sizeof(int) * N_NODES, stream);
    deg_kernel<<<dim3((N_EDGES + 255) / 256), 256, 0, stream>>>(dst, deg);
    block_sum_kernel<<<dim3(NB_SCAN), 256, 0, stream>>>(deg, part);
    part_scan_kernel<<<dim3(1), 256, 0, stream>>>(part, row_ptr);
    row_ptr_kernel<<<dim3(NB_SCAN), 256, 0, stream>>>(deg, part, row_ptr, inv_deg);
    fill_kernel<<<dim3((N_EDGES + 255) / 256), 256, 0, stream>>>(src, dst, row_ptr, cursor, col);

    // --- bf16 conversions ---
    f2bf_kernel<<<dim3((N_NODES * F_IN / 4 + 255) / 256), 256, 0, stream>>>(x, xb, N_NODES * F_IN / 4);
    wtrans<256><<<dim3(256), 256, 0, stream>>>(W1, W1t);
    wtrans<512><<<dim3(256), 256, 0, stream>>>(W2, W2t);

    // --- Layer 1 ---
    agg_mean_bf16<F_IN><<<dim3((N_NODES + 15) / 16), 256, 0, stream>>>(xb, row_ptr, col, inv_deg, xnb);
    gemm_bt_bf16<128, true><<<dim3(M_PAD / 128, 2), 256, 0, stream>>>(xb, xnb, W1t, b1, h1b, N_NODES);

    // --- Layer 2 ---
    agg_mean_bf16<F_HID><<<dim3((N_NODES + 7) / 8), 256, 0, stream>>>(h1b, row_ptr, col, inv_deg, h1nb);
    gemm_bt_bf16<256, false><<<dim3(M_PAD / 128, 2), 256, 0, stream>>>(h1b, h1nb, W2t, b2, out, N_NODES);
}